// Round 6
// baseline (233.825 us; speedup 1.0000x reference)
//
#include <hip/hip_runtime.h>
#include <hip/hip_bf16.h>

// VolatilityModulatedAttention: B=2, S=4096, H=512, NH=8, HD=64
// Round 5: double-buffered K/V DMA (1 barrier/tile, prefetch overlaps
// compute), l-sums via MFMA-with-ones (no per-elem adds, no epilogue
// shuffles), combine fused into proj (Cpart in ws).

#define S_LEN 4096
#define NHEAD 8
#define HD 64
#define HTOT 512

typedef __attribute__((ext_vector_type(8))) short short8;
typedef __attribute__((ext_vector_type(4))) float floatx4;
typedef __attribute__((ext_vector_type(8))) _Float16 half8;

#if __has_builtin(__builtin_amdgcn_exp2f)
#define EXP2F(x) __builtin_amdgcn_exp2f(x)
#else
#define EXP2F(x) exp2f(x)
#endif

__device__ __forceinline__ unsigned pack_bf16(float a, float b) {
    unsigned ua = __builtin_bit_cast(unsigned, a) + 0x8000u;
    unsigned ub = __builtin_bit_cast(unsigned, b) + 0x8000u;
    return __builtin_amdgcn_perm(ub, ua, 0x07060302u);
}

__device__ __forceinline__ unsigned short f2bf(float x) {
    unsigned u = __builtin_bit_cast(unsigned, x) + 0x8000u;
    return (unsigned short)(u >> 16);
}

__device__ __forceinline__ void async16(const unsigned short* g, unsigned short* l) {
    __builtin_amdgcn_global_load_lds(
        (const __attribute__((address_space(1))) unsigned int*)g,
        (__attribute__((address_space(3))) unsigned int*)l, 16, 0, 0);
}

// ---------------------------------------------------------------------------
// Fused prepass. Blocks [0,2048): K fp32 -> bf16. Blocks [2048,3072):
// V fp32 [B,S,512] -> bf16 per-head transpose Vt[B*8][64][4096].
// ---------------------------------------------------------------------------
__global__ __launch_bounds__(256) void prep_kernel(
    const float* __restrict__ K, unsigned short* __restrict__ K16,
    const float* __restrict__ V, unsigned short* __restrict__ Vt)
{
    const int tid = threadIdx.x;
    if (blockIdx.x < 2048) {
        size_t i = ((size_t)blockIdx.x * 256 + tid) * 8;
        float4 a = *(const float4*)(K + i);
        float4 b = *(const float4*)(K + i + 4);
        unsigned o[4] = {pack_bf16(a.x, a.y), pack_bf16(a.z, a.w),
                         pack_bf16(b.x, b.y), pack_bf16(b.z, b.w)};
        *(short8*)(K16 + i) = *(short8*)o;
    } else {
        __shared__ unsigned short T[64 * 66];   // [d][s]
        const int blk = blockIdx.x - 2048;
        const int st = blk & 63;
        const int bh = blk >> 6;
        const int b = bh >> 3, h = bh & 7;
        const float* src = V + ((size_t)b * S_LEN + st * 64) * HTOT + h * HD;
        for (int i = 0; i < 4; i++) {
            int idx = tid + i * 256;
            int s = idx >> 4, c4 = idx & 15;
            float4 v = *(const float4*)(src + (size_t)s * HTOT + c4 * 4);
            T[(c4 * 4 + 0) * 66 + s] = f2bf(v.x);
            T[(c4 * 4 + 1) * 66 + s] = f2bf(v.y);
            T[(c4 * 4 + 2) * 66 + s] = f2bf(v.z);
            T[(c4 * 4 + 3) * 66 + s] = f2bf(v.w);
        }
        __syncthreads();
        unsigned short* dst = Vt + ((size_t)bh * 64) * S_LEN + st * 64;
        for (int i = 0; i < 2; i++) {
            int idx = tid + i * 256;
            int d = idx >> 3, c8 = idx & 7;
            uint2 lo = *(const uint2*)&T[d * 66 + c8 * 8];
            uint2 hi = *(const uint2*)&T[d * 66 + c8 * 8 + 4];
            unsigned o[4] = {lo.x, lo.y, hi.x, hi.y};
            *(short8*)(dst + (size_t)d * S_LEN + c8 * 8) = *(short8*)o;
        }
    }
}

// ---------------------------------------------------------------------------
// Flash attention, K-split x2, double-buffered DMA. Grid: 1024.
// ---------------------------------------------------------------------------
__global__ __launch_bounds__(256) void attn_kernel(
    const float* __restrict__ Q, const unsigned short* __restrict__ K16,
    const unsigned short* __restrict__ Vt,
    const float* __restrict__ risk_sigma, const float* __restrict__ risk_lambda,
    _Float16* __restrict__ Cpart, float* __restrict__ Lpart)
{
    __shared__ unsigned short QPsh[128 * 72];   // Q tile, then per-wave P
    __shared__ unsigned short Ksh[2][64 * 64];  // [key][d] swizzled, dbuf
    __shared__ unsigned short Vsh[2][64 * 64];  // [d][key] swizzled, dbuf

    const int tid  = threadIdx.x;
    const int wave = tid >> 6;
    const int lane = tid & 63;
    const int quad = lane >> 4;
    const int ln   = lane & 15;
    const int sw   = ln & 7;

    const int bid = blockIdx.x;                 // = ((b*8+h)*32+qt)*2+ks
    const int ks  = bid & 1;
    const int qt  = (bid >> 1) & 31;
    const int h   = (bid >> 6) & 7;
    const int b   = bid >> 9;
    const int qbase = qt * 128;

    float sig = risk_sigma[b];
    sig = fminf(fmaxf(sig, 0.001f), 0.2f);
    const float sn   = (sig - 0.001f) * (1.0f / 0.199f);
    const float coef = risk_lambda[0] * 0.1f * sn;
    const float nc2 = -coef * (1.0f / 4096.0f) * (1.0f / 4096.0f) * 1.4426950408889634f;
    const float qscale = 0.125f * 1.4426950408889634f;

    const float* Qb = Q + (size_t)b * S_LEN * HTOT + (size_t)h * HD;
    const unsigned short* Kb = K16 + (size_t)b * S_LEN * HTOT + (size_t)h * HD;
    const unsigned short* Vb = Vt + ((size_t)(b * 8 + h) * 64) * S_LEN;

    // DMA lane geometry
    const int rl  = lane >> 3;
    const int c8g = ((lane & 7) ^ rl) << 3;
    auto dma = [&](int buf, int kbase) {
        const unsigned short* gk = Kb + (size_t)(kbase + wave * 8 + rl) * HTOT + c8g;
        const unsigned short* gv = Vb + (size_t)(wave * 8 + rl) * S_LEN + kbase + c8g;
        async16(gk,              &Ksh[buf][wave * 512 + lane * 8]);
        async16(gk + 32 * HTOT,  &Ksh[buf][(wave + 4) * 512 + lane * 8]);
        async16(gv,              &Vsh[buf][wave * 512 + lane * 8]);
        async16(gv + 32 * S_LEN, &Vsh[buf][(wave + 4) * 512 + lane * 8]);
    };

    // ---- stage Q tile (prescaled fp32 -> bf16) + first DMA ----
    dma(0, ks * 2048);
    for (int i = 0; i < 8; i++) {
        int idx = tid + i * 256;
        int r = idx >> 4, c4 = idx & 15;
        float4 v = *(const float4*)(Qb + (size_t)(qbase + r) * HTOT + c4 * 4);
        uint2 o;
        o.x = pack_bf16(v.x * qscale, v.y * qscale);
        o.y = pack_bf16(v.z * qscale, v.w * qscale);
        *(uint2*)&QPsh[r * 72 + c4 * 4] = o;
    }
    __syncthreads();

    short8 qf[2][2];
    for (int nt = 0; nt < 2; nt++) {
        qf[nt][0] = *(const short8*)&QPsh[(wave * 32 + nt * 16 + ln) * 72 + quad * 8];
        qf[nt][1] = *(const short8*)&QPsh[(wave * 32 + nt * 16 + ln) * 72 + 32 + quad * 8];
    }
    unsigned short* Pw = &QPsh[wave * 32 * 72];

    const short sone = (short)0x3F80;                 // bf16 1.0
    const short8 ones = {sone, sone, sone, sone, sone, sone, sone, sone};

    floatx4 Oacc[2][4], Lacc[2];
    for (int nt = 0; nt < 2; nt++) {
        Lacc[nt] = (floatx4){0.f, 0.f, 0.f, 0.f};
        for (int dt = 0; dt < 4; dt++) Oacc[nt][dt] = (floatx4){0.f, 0.f, 0.f, 0.f};
    }

    const int qa = qbase + wave * 32;

    for (int kt = 0; kt < 32; ++kt) {
        const int kbase = ks * 2048 + kt * 64;
        const int cur = kt & 1;
        if (kt < 31) dma(1 - cur, kbase + 64);        // prefetch next tile
        const unsigned short* Kc = Ksh[cur];
        const unsigned short* Vc = Vsh[cur];

        // ---- S^T = K * Q^T, softmax, packed b64 P write ----
        const float dq = (float)(qa + ln - kbase);
        for (int jt = 0; jt < 4; jt++) {
            const int krow = (jt * 16 + ln) * 64;
            short8 ak0 = *(const short8*)&Kc[krow + ((quad ^ sw) << 3)];
            short8 ak1 = *(const short8*)&Kc[krow + (((quad + 4) ^ sw) << 3)];
            #pragma unroll
            for (int nt = 0; nt < 2; nt++) {
                floatx4 s = (floatx4){0.f, 0.f, 0.f, 0.f};
                s = __builtin_amdgcn_mfma_f32_16x16x32_bf16(ak0, qf[nt][0], s, 0, 0, 0);
                s = __builtin_amdgcn_mfma_f32_16x16x32_bf16(ak1, qf[nt][1], s, 0, 0, 0);
                float d = dq + (float)(nt * 16 - jt * 16 - quad * 4);
                float p[4];
                #pragma unroll
                for (int r = 0; r < 4; r++) {
                    float arg = __builtin_fmaf(nc2, d * d, s[r]);
                    p[r] = EXP2F(arg);
                    d -= 1.0f;
                }
                uint2 o;
                o.x = pack_bf16(p[0], p[1]);
                o.y = pack_bf16(p[2], p[3]);
                *(uint2*)&Pw[(nt * 16 + ln) * 72 + jt * 16 + quad * 4] = o;
            }
        }
        asm volatile("s_waitcnt lgkmcnt(0)" ::: "memory");
        __builtin_amdgcn_wave_barrier();

        // ---- PV + l-sum (B = ones) ----
        short8 pf[2][2];
        for (int nt = 0; nt < 2; nt++) {
            pf[nt][0] = *(const short8*)&Pw[(nt * 16 + ln) * 72 + quad * 8];
            pf[nt][1] = *(const short8*)&Pw[(nt * 16 + ln) * 72 + 32 + quad * 8];
        }
        for (int dt = 0; dt < 4; dt++) {
            const int vrow = (dt * 16 + ln) * 64;
            short8 bv0 = *(const short8*)&Vc[vrow + ((quad ^ sw) << 3)];
            short8 bv1 = *(const short8*)&Vc[vrow + (((quad + 4) ^ sw) << 3)];
            #pragma unroll
            for (int nt = 0; nt < 2; nt++) {
                Oacc[nt][dt] = __builtin_amdgcn_mfma_f32_16x16x32_bf16(pf[nt][0], bv0, Oacc[nt][dt], 0, 0, 0);
                Oacc[nt][dt] = __builtin_amdgcn_mfma_f32_16x16x32_bf16(pf[nt][1], bv1, Oacc[nt][dt], 0, 0, 0);
            }
        }
        #pragma unroll
        for (int nt = 0; nt < 2; nt++) {
            Lacc[nt] = __builtin_amdgcn_mfma_f32_16x16x32_bf16(pf[nt][0], ones, Lacc[nt], 0, 0, 0);
            Lacc[nt] = __builtin_amdgcn_mfma_f32_16x16x32_bf16(pf[nt][1], ones, Lacc[nt], 0, 0, 0);
        }
        __syncthreads();   // reads of cur done; prefetch drained
    }

    // ---- epilogue: l directly from Lacc (row r matches Oacc row r) ----
    _Float16* Cw = Cpart + (size_t)bid * (128 * 64);
    for (int nt = 0; nt < 2; nt++) {
        if (ln == 0) {
            #pragma unroll
            for (int r = 0; r < 4; r++)
                Lpart[bid * 128 + wave * 32 + nt * 16 + quad * 4 + r] = Lacc[nt][r];
        }
        float rl4[4];
        #pragma unroll
        for (int r = 0; r < 4; r++) rl4[r] = 1.0f / Lacc[nt][r];
        for (int dt = 0; dt < 4; dt++)
            #pragma unroll
            for (int r = 0; r < 4; r++) {
                int q = wave * 32 + nt * 16 + quad * 4 + r;
                Cw[q * 64 + dt * 16 + ln] = (_Float16)(Oacc[nt][dt][r] * rl4[r]);
            }
    }
}

// ---------------------------------------------------------------------------
// Projection GEMM with fused K-split combine.
// out[m][n] = sum_k (w0*C0 + w1*C1)[m][k] * W[n][k] + bias[n]
// 64x128 tiles, grid (4,128). A staged by combining fp16 partials.
// ---------------------------------------------------------------------------
__global__ __launch_bounds__(256) void projc_kernel(
    const _Float16* __restrict__ Cpart, const float* __restrict__ Lpart,
    const float* __restrict__ W, const float* __restrict__ bias,
    float* __restrict__ out)
{
    __shared__ unsigned short Ash[64 * 40];
    __shared__ unsigned short Bsh[128 * 40];
    __shared__ float2 Lw[8][64];               // [head][row] (w0,w1)

    const int tid = threadIdx.x;
    const int wave = tid >> 6, lane = tid & 63, quad = lane >> 4, ln = lane & 15;
    const int wr = wave >> 1, wc = wave & 1;
    const int m0 = blockIdx.y * 64;
    const int nb = blockIdx.x * 128;
    const int b = m0 >> 12, qt = (m0 >> 7) & 31, qoff = m0 & 127;  // 0 or 64

    for (int i = 0; i < 2; i++) {
        int e = tid + i * 256;                 // 512 (h,row) pairs
        int hh = e >> 6, r = e & 63;
        int tile = (b * 8 + hh) * 32 + qt;
        float l0 = Lpart[(size_t)(tile * 2 + 0) * 128 + qoff + r];
        float l1 = Lpart[(size_t)(tile * 2 + 1) * 128 + qoff + r];
        float inv = 1.0f / (l0 + l1);
        Lw[hh][r] = (float2){l0 * inv, l1 * inv};
    }

    floatx4 acc[2][4];
    for (int i = 0; i < 2; i++)
        for (int j = 0; j < 4; j++) acc[i][j] = (floatx4){0.f, 0.f, 0.f, 0.f};

    const int ar = tid >> 2, ac8 = tid & 3;    // A-staging coords

    for (int kt = 0; kt < 16; ++kt) {
        const int k0 = kt * 32;
        const int h = k0 >> 6, d0 = k0 & 63;
        __syncthreads();
        {   // A tile: combine fp16 partials -> bf16
            int tile = (b * 8 + h) * 32 + qt;
            const _Float16* C0 = Cpart + (size_t)(tile * 2) * (128 * 64)
                                 + (size_t)(qoff + ar) * 64 + d0 + ac8 * 8;
            const _Float16* C1 = C0 + 128 * 64;
            half8 a0 = *(const half8*)C0;
            half8 a1 = *(const half8*)C1;
            float2 w = Lw[h][ar];
            unsigned o[4];
            #pragma unroll
            for (int k = 0; k < 4; k++) {
                float v0 = w.x * (float)a0[2 * k]     + w.y * (float)a1[2 * k];
                float v1 = w.x * (float)a0[2 * k + 1] + w.y * (float)a1[2 * k + 1];
                o[k] = pack_bf16(v0, v1);
            }
            *(short8*)&Ash[ar * 40 + ac8 * 8] = *(short8*)o;
        }
        for (int i = 0; i < 4; i++) {   // W tile: 128 rows x 32 k fp32->bf16
            int idx = tid + i * 256;
            int r = idx >> 3, c4 = idx & 7;
            float4 v = *(const float4*)&W[(size_t)(nb + r) * 512 + k0 + c4 * 4];
            uint2 o;
            o.x = pack_bf16(v.x, v.y);
            o.y = pack_bf16(v.z, v.w);
            *(uint2*)&Bsh[r * 40 + c4 * 4] = o;
        }
        __syncthreads();
        short8 af[2], bf[4];
        for (int i = 0; i < 2; i++)
            af[i] = *(const short8*)&Ash[(wr * 32 + i * 16 + ln) * 40 + quad * 8];
        for (int j = 0; j < 4; j++)
            bf[j] = *(const short8*)&Bsh[(wc * 64 + j * 16 + ln) * 40 + quad * 8];
        for (int i = 0; i < 2; i++)
            for (int j = 0; j < 4; j++)
                acc[i][j] = __builtin_amdgcn_mfma_f32_16x16x32_bf16(af[i], bf[j], acc[i][j], 0, 0, 0);
    }

    for (int i = 0; i < 2; i++) {
        int row = m0 + wr * 32 + i * 16 + quad * 4;
        for (int j = 0; j < 4; j++) {
            int col = nb + wc * 64 + j * 16 + ln;
            float bv = bias[col];
            #pragma unroll
            for (int r = 0; r < 4; r++)
                out[(size_t)(row + r) * 512 + col] = acc[i][j][r] + bv;
        }
    }
}

extern "C" void kernel_launch(void* const* d_in, const int* in_sizes, int n_in,
                              void* d_out, int out_size, void* d_ws, size_t ws_size,
                              hipStream_t stream) {
    const float* Q    = (const float*)d_in[0];
    const float* K    = (const float*)d_in[1];
    const float* V    = (const float*)d_in[2];
    const float* sig  = (const float*)d_in[3];
    const float* lam  = (const float*)d_in[4];
    const float* W    = (const float*)d_in[5];
    const float* bias = (const float*)d_in[6];

    unsigned short* K16 = (unsigned short*)d_ws;                         // 8 MB
    unsigned short* Vt  = (unsigned short*)((char*)d_ws + (8u << 20));   // 8 MB
    _Float16* Cpart     = (_Float16*)((char*)d_ws + (16u << 20));        // 16 MB
    float* Lpart        = (float*)((char*)d_ws + (32u << 20));           // 512 KB
    float* out = (float*)d_out;

    prep_kernel<<<dim3(3072), dim3(256), 0, stream>>>(K, K16, V, Vt);
    attn_kernel<<<dim3(1024), dim3(256), 0, stream>>>(Q, K16, Vt, sig, lam, Cpart, Lpart);
    projc_kernel<<<dim3(4, 128), dim3(256), 0, stream>>>(Cpart, Lpart, W, bias, out);
}

// Round 7
// 228.877 us; speedup vs baseline: 1.0216x; 1.0216x over previous
//
#include <hip/hip_runtime.h>
#include <hip/hip_bf16.h>

// VolatilityModulatedAttention: B=2, S=4096, H=512, NH=8, HD=64
// Round 6: attn unchanged (R5). Tail rebuilt: W pre-converted to bf16 in
// prep; combine un-fused (bandwidth-bound); proj stages A/W via DMA dbuf
// with conflict-free XOR swizzle. Cpart scratch lives in d_out (R4 pattern).

#define S_LEN 4096
#define NHEAD 8
#define HD 64
#define HTOT 512

typedef __attribute__((ext_vector_type(8))) short short8;
typedef __attribute__((ext_vector_type(4))) float floatx4;
typedef __attribute__((ext_vector_type(8))) _Float16 half8;
typedef __attribute__((ext_vector_type(2))) _Float16 half2v;

#if __has_builtin(__builtin_amdgcn_exp2f)
#define EXP2F(x) __builtin_amdgcn_exp2f(x)
#else
#define EXP2F(x) exp2f(x)
#endif

__device__ __forceinline__ unsigned pack_bf16(float a, float b) {
    unsigned ua = __builtin_bit_cast(unsigned, a) + 0x8000u;
    unsigned ub = __builtin_bit_cast(unsigned, b) + 0x8000u;
    return __builtin_amdgcn_perm(ub, ua, 0x07060302u);
}

__device__ __forceinline__ unsigned short f2bf(float x) {
    unsigned u = __builtin_bit_cast(unsigned, x) + 0x8000u;
    return (unsigned short)(u >> 16);
}

__device__ __forceinline__ void async16(const unsigned short* g, unsigned short* l) {
    __builtin_amdgcn_global_load_lds(
        (const __attribute__((address_space(1))) unsigned int*)g,
        (__attribute__((address_space(3))) unsigned int*)l, 16, 0, 0);
}

// ---------------------------------------------------------------------------
// Fused prepass. [0,2048): K fp32->bf16. [2048,3072): V per-head transpose
// Vt[B*8][64][4096]. [3072,3200): W fp32->bf16.
// ---------------------------------------------------------------------------
__global__ __launch_bounds__(256) void prep_kernel(
    const float* __restrict__ K, unsigned short* __restrict__ K16,
    const float* __restrict__ V, unsigned short* __restrict__ Vt,
    const float* __restrict__ W, unsigned short* __restrict__ W16)
{
    const int tid = threadIdx.x;
    if (blockIdx.x >= 3072) {
        size_t i = ((size_t)(blockIdx.x - 3072) * 256 + tid) * 8;
        float4 a = *(const float4*)(W + i);
        float4 b = *(const float4*)(W + i + 4);
        unsigned o[4] = {pack_bf16(a.x, a.y), pack_bf16(a.z, a.w),
                         pack_bf16(b.x, b.y), pack_bf16(b.z, b.w)};
        *(short8*)(W16 + i) = *(short8*)o;
    } else if (blockIdx.x < 2048) {
        size_t i = ((size_t)blockIdx.x * 256 + tid) * 8;
        float4 a = *(const float4*)(K + i);
        float4 b = *(const float4*)(K + i + 4);
        unsigned o[4] = {pack_bf16(a.x, a.y), pack_bf16(a.z, a.w),
                         pack_bf16(b.x, b.y), pack_bf16(b.z, b.w)};
        *(short8*)(K16 + i) = *(short8*)o;
    } else {
        __shared__ unsigned short T[64 * 66];   // [d][s]
        const int blk = blockIdx.x - 2048;
        const int st = blk & 63;
        const int bh = blk >> 6;
        const int b = bh >> 3, h = bh & 7;
        const float* src = V + ((size_t)b * S_LEN + st * 64) * HTOT + h * HD;
        for (int i = 0; i < 4; i++) {
            int idx = tid + i * 256;
            int s = idx >> 4, c4 = idx & 15;
            float4 v = *(const float4*)(src + (size_t)s * HTOT + c4 * 4);
            T[(c4 * 4 + 0) * 66 + s] = f2bf(v.x);
            T[(c4 * 4 + 1) * 66 + s] = f2bf(v.y);
            T[(c4 * 4 + 2) * 66 + s] = f2bf(v.z);
            T[(c4 * 4 + 3) * 66 + s] = f2bf(v.w);
        }
        __syncthreads();
        unsigned short* dst = Vt + ((size_t)bh * 64) * S_LEN + st * 64;
        for (int i = 0; i < 2; i++) {
            int idx = tid + i * 256;
            int d = idx >> 3, c8 = idx & 7;
            uint2 lo = *(const uint2*)&T[d * 66 + c8 * 8];
            uint2 hi = *(const uint2*)&T[d * 66 + c8 * 8 + 4];
            unsigned o[4] = {lo.x, lo.y, hi.x, hi.y};
            *(short8*)(dst + (size_t)d * S_LEN + c8 * 8) = *(short8*)o;
        }
    }
}

// ---------------------------------------------------------------------------
// Flash attention, K-split x2, double-buffered DMA. Grid: 1024. (unchanged R5)
// ---------------------------------------------------------------------------
__global__ __launch_bounds__(256) void attn_kernel(
    const float* __restrict__ Q, const unsigned short* __restrict__ K16,
    const unsigned short* __restrict__ Vt,
    const float* __restrict__ risk_sigma, const float* __restrict__ risk_lambda,
    _Float16* __restrict__ Cpart, float* __restrict__ Lpart)
{
    __shared__ unsigned short QPsh[128 * 72];
    __shared__ unsigned short Ksh[2][64 * 64];
    __shared__ unsigned short Vsh[2][64 * 64];

    const int tid  = threadIdx.x;
    const int wave = tid >> 6;
    const int lane = tid & 63;
    const int quad = lane >> 4;
    const int ln   = lane & 15;
    const int sw   = ln & 7;

    const int bid = blockIdx.x;                 // = ((b*8+h)*32+qt)*2+ks
    const int ks  = bid & 1;
    const int qt  = (bid >> 1) & 31;
    const int h   = (bid >> 6) & 7;
    const int b   = bid >> 9;
    const int qbase = qt * 128;

    float sig = risk_sigma[b];
    sig = fminf(fmaxf(sig, 0.001f), 0.2f);
    const float sn   = (sig - 0.001f) * (1.0f / 0.199f);
    const float coef = risk_lambda[0] * 0.1f * sn;
    const float nc2 = -coef * (1.0f / 4096.0f) * (1.0f / 4096.0f) * 1.4426950408889634f;
    const float qscale = 0.125f * 1.4426950408889634f;

    const float* Qb = Q + (size_t)b * S_LEN * HTOT + (size_t)h * HD;
    const unsigned short* Kb = K16 + (size_t)b * S_LEN * HTOT + (size_t)h * HD;
    const unsigned short* Vb = Vt + ((size_t)(b * 8 + h) * 64) * S_LEN;

    const int rl  = lane >> 3;
    const int c8g = ((lane & 7) ^ rl) << 3;
    auto dma = [&](int buf, int kbase) {
        const unsigned short* gk = Kb + (size_t)(kbase + wave * 8 + rl) * HTOT + c8g;
        const unsigned short* gv = Vb + (size_t)(wave * 8 + rl) * S_LEN + kbase + c8g;
        async16(gk,              &Ksh[buf][wave * 512 + lane * 8]);
        async16(gk + 32 * HTOT,  &Ksh[buf][(wave + 4) * 512 + lane * 8]);
        async16(gv,              &Vsh[buf][wave * 512 + lane * 8]);
        async16(gv + 32 * S_LEN, &Vsh[buf][(wave + 4) * 512 + lane * 8]);
    };

    dma(0, ks * 2048);
    for (int i = 0; i < 8; i++) {
        int idx = tid + i * 256;
        int r = idx >> 4, c4 = idx & 15;
        float4 v = *(const float4*)(Qb + (size_t)(qbase + r) * HTOT + c4 * 4);
        uint2 o;
        o.x = pack_bf16(v.x * qscale, v.y * qscale);
        o.y = pack_bf16(v.z * qscale, v.w * qscale);
        *(uint2*)&QPsh[r * 72 + c4 * 4] = o;
    }
    __syncthreads();

    short8 qf[2][2];
    for (int nt = 0; nt < 2; nt++) {
        qf[nt][0] = *(const short8*)&QPsh[(wave * 32 + nt * 16 + ln) * 72 + quad * 8];
        qf[nt][1] = *(const short8*)&QPsh[(wave * 32 + nt * 16 + ln) * 72 + 32 + quad * 8];
    }
    unsigned short* Pw = &QPsh[wave * 32 * 72];

    const short sone = (short)0x3F80;
    const short8 ones = {sone, sone, sone, sone, sone, sone, sone, sone};

    floatx4 Oacc[2][4], Lacc[2];
    for (int nt = 0; nt < 2; nt++) {
        Lacc[nt] = (floatx4){0.f, 0.f, 0.f, 0.f};
        for (int dt = 0; dt < 4; dt++) Oacc[nt][dt] = (floatx4){0.f, 0.f, 0.f, 0.f};
    }

    const int qa = qbase + wave * 32;

    for (int kt = 0; kt < 32; ++kt) {
        const int kbase = ks * 2048 + kt * 64;
        const int cur = kt & 1;
        if (kt < 31) dma(1 - cur, kbase + 64);
        const unsigned short* Kc = Ksh[cur];
        const unsigned short* Vc = Vsh[cur];

        const float dq = (float)(qa + ln - kbase);
        for (int jt = 0; jt < 4; jt++) {
            const int krow = (jt * 16 + ln) * 64;
            short8 ak0 = *(const short8*)&Kc[krow + ((quad ^ sw) << 3)];
            short8 ak1 = *(const short8*)&Kc[krow + (((quad + 4) ^ sw) << 3)];
            #pragma unroll
            for (int nt = 0; nt < 2; nt++) {
                floatx4 s = (floatx4){0.f, 0.f, 0.f, 0.f};
                s = __builtin_amdgcn_mfma_f32_16x16x32_bf16(ak0, qf[nt][0], s, 0, 0, 0);
                s = __builtin_amdgcn_mfma_f32_16x16x32_bf16(ak1, qf[nt][1], s, 0, 0, 0);
                float d = dq + (float)(nt * 16 - jt * 16 - quad * 4);
                float p[4];
                #pragma unroll
                for (int r = 0; r < 4; r++) {
                    float arg = __builtin_fmaf(nc2, d * d, s[r]);
                    p[r] = EXP2F(arg);
                    d -= 1.0f;
                }
                uint2 o;
                o.x = pack_bf16(p[0], p[1]);
                o.y = pack_bf16(p[2], p[3]);
                *(uint2*)&Pw[(nt * 16 + ln) * 72 + jt * 16 + quad * 4] = o;
            }
        }
        asm volatile("s_waitcnt lgkmcnt(0)" ::: "memory");
        __builtin_amdgcn_wave_barrier();

        short8 pf[2][2];
        for (int nt = 0; nt < 2; nt++) {
            pf[nt][0] = *(const short8*)&Pw[(nt * 16 + ln) * 72 + quad * 8];
            pf[nt][1] = *(const short8*)&Pw[(nt * 16 + ln) * 72 + 32 + quad * 8];
        }
        for (int dt = 0; dt < 4; dt++) {
            const int vrow = (dt * 16 + ln) * 64;
            short8 bv0 = *(const short8*)&Vc[vrow + ((quad ^ sw) << 3)];
            short8 bv1 = *(const short8*)&Vc[vrow + (((quad + 4) ^ sw) << 3)];
            #pragma unroll
            for (int nt = 0; nt < 2; nt++) {
                Oacc[nt][dt] = __builtin_amdgcn_mfma_f32_16x16x32_bf16(pf[nt][0], bv0, Oacc[nt][dt], 0, 0, 0);
                Oacc[nt][dt] = __builtin_amdgcn_mfma_f32_16x16x32_bf16(pf[nt][1], bv1, Oacc[nt][dt], 0, 0, 0);
            }
        }
        #pragma unroll
        for (int nt = 0; nt < 2; nt++) {
            Lacc[nt] = __builtin_amdgcn_mfma_f32_16x16x32_bf16(pf[nt][0], ones, Lacc[nt], 0, 0, 0);
            Lacc[nt] = __builtin_amdgcn_mfma_f32_16x16x32_bf16(pf[nt][1], ones, Lacc[nt], 0, 0, 0);
        }
        __syncthreads();
    }

    _Float16* Cw = Cpart + (size_t)bid * (128 * 64);
    for (int nt = 0; nt < 2; nt++) {
        if (ln == 0) {
            #pragma unroll
            for (int r = 0; r < 4; r++)
                Lpart[bid * 128 + wave * 32 + nt * 16 + quad * 4 + r] = Lacc[nt][r];
        }
        float rl4[4];
        #pragma unroll
        for (int r = 0; r < 4; r++) rl4[r] = 1.0f / Lacc[nt][r];
        for (int dt = 0; dt < 4; dt++)
            #pragma unroll
            for (int r = 0; r < 4; r++) {
                int q = wave * 32 + nt * 16 + quad * 4 + r;
                Cw[q * 64 + dt * 16 + ln] = (_Float16)(Oacc[nt][dt][r] * rl4[r]);
            }
    }
}

// ---------------------------------------------------------------------------
// Combine: ctx = w0*C0 + w1*C1, w_ks = l_ks/(l0+l1). Grid 512 tiles.
// ---------------------------------------------------------------------------
__global__ __launch_bounds__(256) void combine_kernel(
    const _Float16* __restrict__ Cpart, const float* __restrict__ Lpart,
    unsigned short* __restrict__ ctx)
{
    const int t = threadIdx.x;
    const int tile = blockIdx.x;              // (b*8+h)*32+qt
    const int qt = tile & 31, h = (tile >> 5) & 7, b = tile >> 8;
    __shared__ float w0s[128], w1s[128];
    if (t < 128) {
        float l0 = Lpart[(tile * 2 + 0) * 128 + t];
        float l1 = Lpart[(tile * 2 + 1) * 128 + t];
        float inv = 1.0f / (l0 + l1);
        w0s[t] = l0 * inv;
        w1s[t] = l1 * inv;
    }
    __syncthreads();
    const _Float16* C0 = Cpart + (size_t)(tile * 2) * (128 * 64);
    const _Float16* C1 = C0 + 128 * 64;
    for (int i = 0; i < 8; i++) {
        int e = (i * 256 + t) * 4;
        int q = e >> 6, d = e & 63;
        half2v a0 = *(const half2v*)(C0 + e);
        half2v a1 = *(const half2v*)(C0 + e + 2);
        half2v b0 = *(const half2v*)(C1 + e);
        half2v b1 = *(const half2v*)(C1 + e + 2);
        float w0 = w0s[q], w1 = w1s[q];
        float v0 = w0 * (float)a0[0] + w1 * (float)b0[0];
        float v1 = w0 * (float)a0[1] + w1 * (float)b0[1];
        float v2 = w0 * (float)a1[0] + w1 * (float)b1[0];
        float v3 = w0 * (float)a1[1] + w1 * (float)b1[1];
        uint2 o;
        o.x = pack_bf16(v0, v1);
        o.y = pack_bf16(v2, v3);
        *(uint2*)&ctx[((size_t)b * S_LEN + qt * 128 + q) * HTOT + h * HD + d] = o;
    }
}

// ---------------------------------------------------------------------------
// Projection GEMM, all-bf16, DMA double-buffered staging.
// out[m][n] = sum_k ctx[m][k]*W16[n][k] + bias[n]. 64x128 tiles, grid (4,128).
// LDS rows are 32 shorts (64B = 4 chunks); chunk swizzle key s(row)=(row>>1)&3
// gives conflict-free b128 frag reads (8 distinct 4-bank spans / 16 lanes).
// ---------------------------------------------------------------------------
__global__ __launch_bounds__(256) void proj_kernel(
    const unsigned short* __restrict__ A,   // ctx bf16 [8192 x 512]
    const unsigned short* __restrict__ W16, // [512 x 512] bf16
    const float* __restrict__ bias,
    float* __restrict__ out)
{
    __shared__ unsigned short Ash[2][64 * 32];
    __shared__ unsigned short Bsh[2][128 * 32];
    const int tid = threadIdx.x;
    const int wave = tid >> 6, lane = tid & 63, quad = lane >> 4, ln = lane & 15;
    const int wr = wave >> 1, wc = wave & 1;
    const int m0 = blockIdx.y * 64;
    const int nb = blockIdx.x * 128;

    // DMA lane geometry: A rows (64): gi = wave*64+lane -> row=gi>>2, c=gi&3
    const int arow = (wave * 64 + lane) >> 2;
    const int ac   = (wave * 64 + lane) & 3;
    const int acs  = (ac ^ ((arow >> 1) & 3)) << 3;   // swizzled k-chunk (shorts)
    const int wrow0 = (wave * 64 + lane) >> 2;        // W rows for i=0 (0..63)
    const int wc0   = (wave * 64 + lane) & 3;
    const int wcs0  = (wc0 ^ ((wrow0 >> 1) & 3)) << 3;
    const int wrow1 = wrow0 + 64;
    const int wcs1  = (wc0 ^ ((wrow1 >> 1) & 3)) << 3;

    auto dma = [&](int buf, int k0) {
        async16(A + (size_t)(m0 + arow) * 512 + k0 + acs,
                &Ash[buf][wave * 512 + lane * 8]);
        async16(W16 + (size_t)(nb + wrow0) * 512 + k0 + wcs0,
                &Bsh[buf][wave * 512 + lane * 8]);
        async16(W16 + (size_t)(nb + wrow1) * 512 + k0 + wcs1,
                &Bsh[buf][(wave + 4) * 512 + lane * 8]);
    };

    floatx4 acc[2][4];
    for (int i = 0; i < 2; i++)
        for (int j = 0; j < 4; j++) acc[i][j] = (floatx4){0.f, 0.f, 0.f, 0.f};

    dma(0, 0);
    for (int kt = 0; kt < 16; ++kt) {
        const int cur = kt & 1;
        __syncthreads();                       // drain cur's DMA; 1-cur reads done
        if (kt < 15) dma(1 - cur, (kt + 1) * 32);

        short8 af[2], bf[4];
        for (int i = 0; i < 2; i++) {
            int r = wr * 32 + i * 16 + ln;
            af[i] = *(const short8*)&Ash[cur][r * 32 + ((quad ^ ((r >> 1) & 3)) << 3)];
        }
        for (int j = 0; j < 4; j++) {
            int r = wc * 64 + j * 16 + ln;
            bf[j] = *(const short8*)&Bsh[cur][r * 32 + ((quad ^ ((r >> 1) & 3)) << 3)];
        }
        for (int i = 0; i < 2; i++)
            for (int j = 0; j < 4; j++)
                acc[i][j] = __builtin_amdgcn_mfma_f32_16x16x32_bf16(af[i], bf[j], acc[i][j], 0, 0, 0);
    }

    for (int i = 0; i < 2; i++) {
        int row = m0 + wr * 32 + i * 16 + quad * 4;
        for (int j = 0; j < 4; j++) {
            int col = nb + wc * 64 + j * 16 + ln;
            float bv = bias[col];
            #pragma unroll
            for (int r = 0; r < 4; r++)
                out[(size_t)(row + r) * 512 + col] = acc[i][j][r] + bv;
        }
    }
}

extern "C" void kernel_launch(void* const* d_in, const int* in_sizes, int n_in,
                              void* d_out, int out_size, void* d_ws, size_t ws_size,
                              hipStream_t stream) {
    const float* Q    = (const float*)d_in[0];
    const float* K    = (const float*)d_in[1];
    const float* V    = (const float*)d_in[2];
    const float* sig  = (const float*)d_in[3];
    const float* lam  = (const float*)d_in[4];
    const float* W    = (const float*)d_in[5];
    const float* bias = (const float*)d_in[6];

    unsigned short* K16 = (unsigned short*)d_ws;                          // 8 MB
    unsigned short* Vt  = (unsigned short*)((char*)d_ws + (8u << 20));    // 8 MB
    unsigned short* ctx = (unsigned short*)((char*)d_ws + (16u << 20));   // 8 MB
    float* Lpart        = (float*)((char*)d_ws + (24u << 20));            // 512 KB
    unsigned short* W16 = (unsigned short*)((char*)d_ws + (24u << 20) + (512u << 10)); // 512 KB
    _Float16* Cpart     = (_Float16*)d_out;   // 16 MB scratch, overwritten by proj
    float* out = (float*)d_out;

    prep_kernel<<<dim3(3200), dim3(256), 0, stream>>>(K, K16, V, Vt, W, W16);
    attn_kernel<<<dim3(1024), dim3(256), 0, stream>>>(Q, K16, Vt, sig, lam, Cpart, Lpart);
    combine_kernel<<<dim3(512), dim3(256), 0, stream>>>(Cpart, Lpart, ctx);
    proj_kernel<<<dim3(4, 128), dim3(256), 0, stream>>>(ctx, W16, bias, out);
}